// Round 14
// baseline (204.426 us; speedup 1.0000x reference)
//
#include <hip/hip_runtime.h>
#include <hip/hip_bf16.h>

typedef unsigned short u16;
typedef u16 u16x8 __attribute__((ext_vector_type(8)));
typedef float f32x4 __attribute__((ext_vector_type(4)));
typedef __bf16 bf16x8 __attribute__((ext_vector_type(8)));

#define B_ 4
#define S_ 2048
#define D_ 1024
#define H_ 16
#define HD_ 64
#define M_ (B_*S_)

#if __has_builtin(__builtin_amdgcn_exp2f)
#define EXP2(x) __builtin_amdgcn_exp2f(x)
#else
#define EXP2(x) exp2f(x)
#endif

__device__ __forceinline__ f32x4 MFMA(u16x8 a, u16x8 b, f32x4 c) {
  return __builtin_amdgcn_mfma_f32_16x16x32_bf16(
      __builtin_bit_cast(bf16x8, a), __builtin_bit_cast(bf16x8, b), c, 0, 0, 0);
}

__device__ __forceinline__ u16 f2b(float f) {
  return __builtin_bit_cast(u16, __float2bfloat16(f));
}

__device__ __forceinline__ void load_lds16(const void* g, void* l) {
  __builtin_amdgcn_global_load_lds(
      (const __attribute__((address_space(1))) void*)g,
      (__attribute__((address_space(3))) void*)l, 16, 0, 0);
}

__device__ __forceinline__ unsigned int cvtpk(float lo, float hi) {
  unsigned int r;
  asm("v_cvt_pk_bf16_f32 %0, %1, %2" : "=v"(r) : "v"(lo), "v"(hi));
  return r;
}

// ======== Fused prep: rope table | f32->bf16 cvt | 4x W transpose ========
// blocks [0,4096): rope tab; [4096,12288): cvt; [12288,16384): transpose.
__global__ __launch_bounds__(256) void k_prep(
    const float* __restrict__ x, u16* __restrict__ xb,
    const float* __restrict__ Wq, const float* __restrict__ Wk,
    const float* __restrict__ Wv, const float* __restrict__ W0,
    u16* __restrict__ Tq, u16* __restrict__ Tk, u16* __restrict__ Tv,
    u16* __restrict__ T0, float2* __restrict__ tab) {
  __shared__ float t[32][33];
  const int bid = blockIdx.x;
  const int tid = threadIdx.x;
  if (bid < 4096) {
    int i = bid * 256 + tid;
    int s = i >> 9;
    int f = i & 511;
    float invf = exp2f((float)f * (-13.287712379549449f / 512.0f));
    float ang = (float)s * invf;
    tab[i] = make_float2(cosf(ang), sinf(ang));
  } else if (bid < 12288) {
    int i = (bid - 4096) * 256 + tid;
    float4 v = ((const float4*)x)[i];
    ushort4 o;
    o.x = f2b(v.x); o.y = f2b(v.y); o.z = f2b(v.z); o.w = f2b(v.w);
    ((ushort4*)xb)[i] = o;
  } else {
    const int bid2 = bid - 12288;
    const int z = bid2 >> 10, rem = bid2 & 1023;
    const float* W = (z == 0) ? Wq : (z == 1) ? Wk : (z == 2) ? Wv : W0;
    u16* WT = (z == 0) ? Tq : (z == 1) ? Tk : (z == 2) ? Tv : T0;
    const int tx = tid & 31, ty = tid >> 5;  // 32 x 8
    const int bx = (rem & 31) * 32, by = (rem >> 5) * 32;
#pragma unroll
    for (int j = 0; j < 32; j += 8)
      t[ty + j][tx] = W[(size_t)(by + ty + j) * D_ + bx + tx];
    __syncthreads();
#pragma unroll
    for (int j = 0; j < 32; j += 8)
      WT[(size_t)(bx + ty + j) * D_ + by + tx] = f2b(t[tx][ty + j]);
  }
}

// ===== 256x256 QKV GEMM, single-buffer LDS (64KB -> 2 blk/CU, all 384 ====
// blocks resident). Per K-tile: barrier -> stage 8x global_load_lds ->
// barrier (vmcnt drain) -> 4 lockstep MFMA phases. Stage stall hidden by
// the co-resident second block (TLP), not intra-block dbuf.
__global__ __launch_bounds__(512, 2) void k_gemm256_qkv(
    const u16* __restrict__ A, const u16* __restrict__ BT,
    const float* __restrict__ bq, const float* __restrict__ bk,
    const float* __restrict__ bv, const float2* __restrict__ tab,
    u16* __restrict__ Qh, u16* __restrict__ Kh, u16* __restrict__ Vt) {
  __shared__ __attribute__((aligned(16))) u16 Al[16384];
  __shared__ __attribute__((aligned(16))) u16 Bl[16384];
  const int tid = threadIdx.x;
  const int lane = tid & 63, wid = tid >> 6;
  const int wm = wid >> 2, wn = wid & 3;
  const int g = lane >> 4, c = lane & 15;
  const int flat = blockIdx.x;
  const int xcd = flat & 7, idx = flat >> 3;
  const int bx = xcd * 4 + (idx & 3), by = idx >> 2;
  const int rowbase = bx * 256;

  const int rr_ = tid >> 3, slot = tid & 7;
  const int sw8 = slot ^ (rr_ & 7);
  const u16* aB = A + (size_t)(rowbase + rr_) * 1024 + sw8 * 8;
  const u16* bB = BT + (size_t)(by * 256 + rr_) * 1024 + sw8 * 8;
  const int wdst = wid * 512;

  f32x4 acc[8][4] = {};
  const int swz = (c & 7) << 3;
  const int k0o = (g * 8) ^ swz;
  const int k1o = k0o ^ 32;
  const int ArdB = (wm * 128 + c) * 64;
  const int BrdB = (wn * 64 + c) * 64;

  u16x8 bf00, bf01, bf10, bf11, bf20, bf21, bf30, bf31;

#define ISSUE_ALL(KT)                                                        \
  load_lds16(aB + (KT), &Al[wdst]);                                          \
  load_lds16(aB + 65536 + (KT), &Al[4096 + wdst]);                           \
  load_lds16(aB + 131072 + (KT), &Al[8192 + wdst]);                          \
  load_lds16(aB + 196608 + (KT), &Al[12288 + wdst]);                         \
  load_lds16(bB + (KT), &Bl[wdst]);                                          \
  load_lds16(bB + 65536 + (KT), &Bl[4096 + wdst]);                           \
  load_lds16(bB + 131072 + (KT), &Bl[8192 + wdst]);                          \
  load_lds16(bB + 196608 + (KT), &Bl[12288 + wdst]);
#define PBAR                                                                 \
  __builtin_amdgcn_sched_barrier(0);                                         \
  __builtin_amdgcn_s_barrier();                                              \
  asm volatile("s_waitcnt lgkmcnt(0)" ::: "memory");                         \
  __builtin_amdgcn_sched_barrier(0);                                         \
  __builtin_amdgcn_s_setprio(1);
#define PEND                                                                 \
  __builtin_amdgcn_s_setprio(0);                                             \
  __builtin_amdgcn_sched_barrier(0);                                         \
  __builtin_amdgcn_s_barrier();
#define LDB8                                                                 \
  bf00 = *(const u16x8*)&Bl[BrdB + k0o];                                     \
  bf01 = *(const u16x8*)&Bl[BrdB + k1o];                                     \
  bf10 = *(const u16x8*)&Bl[BrdB + 1024 + k0o];                              \
  bf11 = *(const u16x8*)&Bl[BrdB + 1024 + k1o];                              \
  bf20 = *(const u16x8*)&Bl[BrdB + 2048 + k0o];                              \
  bf21 = *(const u16x8*)&Bl[BrdB + 2048 + k1o];                              \
  bf30 = *(const u16x8*)&Bl[BrdB + 3072 + k0o];                              \
  bf31 = *(const u16x8*)&Bl[BrdB + 3072 + k1o];
#define LDA4(MI0)                                                            \
  a00 = *(const u16x8*)&Al[ArdB + (MI0) * 1024 + k0o];                       \
  a01 = *(const u16x8*)&Al[ArdB + (MI0) * 1024 + k1o];                       \
  a10 = *(const u16x8*)&Al[ArdB + (MI0 + 1) * 1024 + k0o];                   \
  a11 = *(const u16x8*)&Al[ArdB + (MI0 + 1) * 1024 + k1o];
#define MFMA16(MI0)                                                          \
  acc[MI0][0] = MFMA(a00, bf00, acc[MI0][0]);                                \
  acc[MI0][0] = MFMA(a01, bf01, acc[MI0][0]);                                \
  acc[MI0][1] = MFMA(a00, bf10, acc[MI0][1]);                                \
  acc[MI0][1] = MFMA(a01, bf11, acc[MI0][1]);                                \
  acc[MI0][2] = MFMA(a00, bf20, acc[MI0][2]);                                \
  acc[MI0][2] = MFMA(a01, bf21, acc[MI0][2]);                                \
  acc[MI0][3] = MFMA(a00, bf30, acc[MI0][3]);                                \
  acc[MI0][3] = MFMA(a01, bf31, acc[MI0][3]);                                \
  acc[MI0 + 1][0] = MFMA(a10, bf00, acc[MI0 + 1][0]);                        \
  acc[MI0 + 1][0] = MFMA(a11, bf01, acc[MI0 + 1][0]);                        \
  acc[MI0 + 1][1] = MFMA(a10, bf10, acc[MI0 + 1][1]);                        \
  acc[MI0 + 1][1] = MFMA(a11, bf11, acc[MI0 + 1][1]);                        \
  acc[MI0 + 1][2] = MFMA(a10, bf20, acc[MI0 + 1][2]);                        \
  acc[MI0 + 1][2] = MFMA(a11, bf21, acc[MI0 + 1][2]);                        \
  acc[MI0 + 1][3] = MFMA(a10, bf30, acc[MI0 + 1][3]);                        \
  acc[MI0 + 1][3] = MFMA(a11, bf31, acc[MI0 + 1][3]);

#pragma unroll 1
  for (int kt = 0; kt < 16; ++kt) {
    if (kt) __syncthreads();  // all waves done reading previous tile
    ISSUE_ALL(kt * 64)
    __syncthreads();          // vmcnt drained -> staged tile visible
    u16x8 a00, a01, a10, a11;
    LDB8 LDA4(0)
    PBAR MFMA16(0) PEND
    LDA4(2) PBAR MFMA16(2) PEND
    LDA4(4) PBAR MFMA16(4) PEND
    LDA4(6) PBAR MFMA16(6)
    __builtin_amdgcn_s_setprio(0);
  }

  const int mode = by >> 2;
  const float* bias = (mode == 0) ? bq : (mode == 1) ? bk : bv;
  u16* Cout = (mode == 0) ? Qh : (mode == 1) ? Kh : Vt;
  const int colL0 = (by & 3) * 256 + wn * 64;
  int coln[4];
  float bn[4];
#pragma unroll
  for (int ni = 0; ni < 4; ++ni) {
    coln[ni] = colL0 + ni * 16 + c;
    bn[ni] = bias[coln[ni]];
  }
  if (mode == 2) {
#pragma unroll
    for (int mi = 0; mi < 8; ++mi) {
      const int row0 = rowbase + wm * 128 + mi * 16 + g * 4;
      const int s0 = row0 & (S_ - 1);
      const int bidx = row0 >> 11;
#pragma unroll
      for (int ni = 0; ni < 4; ++ni) {
        const int h = coln[ni] >> 6, hd = coln[ni] & 63;
        ushort4 w;
        w.x = f2b(acc[mi][ni][0] + bn[ni]);
        w.y = f2b(acc[mi][ni][1] + bn[ni]);
        w.z = f2b(acc[mi][ni][2] + bn[ni]);
        w.w = f2b(acc[mi][ni][3] + bn[ni]);
        *(ushort4*)(Cout + ((size_t)(bidx * H_ + h) * HD_ + hd) * S_ + s0) = w;
      }
    }
  } else {
    const float qs = 0.18033688011112042f;  // 0.125 * log2(e)
#pragma unroll
    for (int mi = 0; mi < 8; ++mi) {
#pragma unroll
      for (int rq = 0; rq < 4; ++rq) {
        const int row = rowbase + wm * 128 + mi * 16 + g * 4 + rq;
        const int s = row & (S_ - 1);
        const int bidx = row >> 11;
#pragma unroll
        for (int ni = 0; ni < 4; ++ni) {
          float v = acc[mi][ni][rq] + bn[ni];
          float2 cs = tab[(size_t)s * 512 + (coln[ni] >> 1)];
          float nb = __shfl_xor(v, 1);
          v = (lane & 1) ? (nb * cs.y + v * cs.x) : (v * cs.x - nb * cs.y);
          if (mode == 0) v *= qs;
          const int h = coln[ni] >> 6, hd = coln[ni] & 63;
          Cout[(((size_t)(bidx * H_ + h)) * S_ + s) * HD_ + hd] = f2b(v);
        }
      }
    }
  }
#undef MFMA16
#undef LDA4
#undef LDB8
#undef PEND
#undef PBAR
#undef ISSUE_ALL
}

// ------- Output GEMM: 128x128 m97-style, 2 blk/CU, grid 512 = 2 rounds ---
__global__ __launch_bounds__(256, 2) void k_gemm_o(
    const u16* __restrict__ A, const u16* __restrict__ BT,
    const float* __restrict__ bias, float* __restrict__ Cout) {
  __shared__ __attribute__((aligned(16))) u16 Al[128 * 64];
  __shared__ __attribute__((aligned(16))) u16 Bl[128 * 64];
  const int tid = threadIdx.x;
  const int lane = tid & 63, wid = tid >> 6;
  const int wr = wid >> 1, wc = wid & 1;
  const int g = lane >> 4, c = lane & 15;
  const int flat = blockIdx.y * gridDim.x + blockIdx.x;
  const int xcd = flat & 7, idx = flat >> 3;
  const int bx = xcd * 8 + (idx & 7), by = idx >> 3;  // bx<64, by<8
  const int rowbase = bx * 128, colbase = by * 128;

  f32x4 acc[4][4] = {};
  const int ldr = lane >> 3;
  const int ldk = (lane & 7) * 8;

  for (int kt = 0; kt < D_; kt += 64) {
    __syncthreads();
#pragma unroll
    for (int j = 0; j < 4; ++j) {
      const int chunk = wid * 4 + j;
      const int rr = chunk * 8 + ldr;
      load_lds16(A + (size_t)(rowbase + rr) * D_ + kt + ldk, &Al[chunk * 512]);
      load_lds16(BT + (size_t)(colbase + rr) * D_ + kt + ldk, &Bl[chunk * 512]);
    }
    __syncthreads();
#pragma unroll
    for (int ks = 0; ks < 2; ++ks) {
      u16x8 a[4], b[4];
#pragma unroll
      for (int m = 0; m < 4; ++m)
        a[m] = *(const u16x8*)&Al[(wr * 64 + m * 16 + c) * 64 + ks * 32 + g * 8];
#pragma unroll
      for (int n = 0; n < 4; ++n)
        b[n] = *(const u16x8*)&Bl[(wc * 64 + n * 16 + c) * 64 + ks * 32 + g * 8];
#pragma unroll
      for (int m = 0; m < 4; ++m)
#pragma unroll
        for (int n = 0; n < 4; ++n)
          acc[m][n] = MFMA(a[m], b[n], acc[m][n]);
    }
  }

  int coln[4];
  float bn[4];
#pragma unroll
  for (int n = 0; n < 4; ++n) {
    coln[n] = colbase + wc * 64 + n * 16 + c;
    bn[n] = bias[coln[n]];
  }
#pragma unroll
  for (int m = 0; m < 4; ++m)
#pragma unroll
    for (int r = 0; r < 4; ++r) {
      const int row = rowbase + wr * 64 + m * 16 + g * 4 + r;
#pragma unroll
      for (int n = 0; n < 4; ++n)
        Cout[(size_t)row * D_ + coln[n]] = acc[m][n][r] + bn[n];
    }
}

// ---------------- Flash attention v9 (unchanged, ~84 us) ----------------
__global__ __launch_bounds__(512, 4) void k_attn(const u16* __restrict__ Qh,
                                                 const u16* __restrict__ Kh,
                                                 const u16* __restrict__ Vt,
                                                 u16* __restrict__ AO) {
  __shared__ __attribute__((aligned(16))) u16 Kl0[4096], Kl1[4096];
  __shared__ __attribute__((aligned(16))) u16 Vl0[4096], Vl1[4096];
  __shared__ __attribute__((aligned(16))) u16 Pl[16384];
  const int tid = threadIdx.x;
  const int lane = tid & 63, wid = tid >> 6;
  const int g = lane >> 4, c = lane & 15;
  const int flat = blockIdx.x;
  const int swzid = (flat & 7) * 64 + (flat >> 3);
  const int bh = swzid >> 3, qt = swzid & 7;
  const size_t base = (size_t)bh * S_ * HD_;
  const int qr0 = qt * 256 + wid * 32;

  u16x8 qf[2][2];
#pragma unroll
  for (int qg = 0; qg < 2; ++qg)
#pragma unroll
    for (int ks = 0; ks < 2; ++ks)
      qf[qg][ks] = *(const u16x8*)(Qh + base +
                                   (size_t)(qr0 + qg * 16 + c) * HD_ +
                                   ks * 32 + g * 8);

  f32x4 o20[4] = {}, o21[4] = {};
  float L0 = 0.f, L1 = 0.f;

  const int swz = (c & 7) << 3;
  const int kb0 = c * 64 + ((g * 8) ^ swz);
  const int kb1 = c * 64 + ((32 + g * 8) ^ swz);
  const int pwA0 = wid * 2048 + ((c * 64 + 0 * 16 + g * 4) ^ swz);
  const int pwA1 = wid * 2048 + ((c * 64 + 1 * 16 + g * 4) ^ swz);
  const int pwA2 = wid * 2048 + ((c * 64 + 2 * 16 + g * 4) ^ swz);
  const int pwA3 = wid * 2048 + ((c * 64 + 3 * 16 + g * 4) ^ swz);
  const int pbA0 = wid * 2048 + kb0;
  const int pbA1 = wid * 2048 + kb1;
  const f32x4 z4 = {0.f, 0.f, 0.f, 0.f};

  const int ldrow = lane >> 3, ldslot = lane & 7;
  const int srow = wid * 8 + ldrow;
  const u16* kp0 = Kh + base + (size_t)srow * HD_ + (ldslot ^ (srow & 7)) * 8;
  const u16* vp0 = Vt + base + (size_t)srow * S_ + (ldslot ^ (srow & 7)) * 8;
  const int kdst0 = wid * 512;

#define STAGE(KP, VP)                                                        \
  {                                                                          \
    load_lds16(kp0, &KP[kdst0]); kp0 += 64 * HD_;                            \
    load_lds16(vp0, &VP[kdst0]); vp0 += 64;                                  \
  }

#define BODY(KC, VC, KP, VP)                                                 \
  {                                                                          \
    STAGE(KP, VP);                                                           \
    f32x4 s40[4], s41[4];                                                    \
    __builtin_amdgcn_s_setprio(1);                                           \
    _Pragma("unroll") for (int n = 0; n < 4; ++n) {                          \
      u16x8 kfa = *(const u16x8*)&KC[n * 1024 + kb0];                        \
      u16x8 kfb = *(const u16x8*)&KC[n * 1024 + kb1];                        \
      s40[n] = MFMA(kfa, qf[0][0], z4);                                      \
      s40[n] = MFMA(kfb, qf[0][1], s40[n]);                                  \
      s41[n] = MFMA(kfa, qf[1][0], z4);                                      \
      s41[n] = MFMA(kfb, qf[1][1], s41[n]);                                  \
    }                                                                        \
    __builtin_amdgcn_s_setprio(0);                                           \
    float rs0 = 0.f, rs1 = 0.f;                                              \
    _Pragma("unroll") for (int n = 0; n < 4; ++n) {                          \
      float p0[4], p1[4];                                                    \
      _Pragma("unroll") for (int r = 0; r < 4; ++r) {                        \
        p0[r] = EXP2(s40[n][r]); rs0 += p0[r];                               \
        p1[r] = EXP2(s41[n][r]); rs1 += p1[r];                               \
      }                                                                      \
      uint2 w0, w1;                                                          \
      w0.x = cvtpk(p0[0], p0[1]); w0.y = cvtpk(p0[2], p0[3]);                \
      w1.x = cvtpk(p1[0], p1[1]); w1.y = cvtpk(p1[2], p1[3]);                \
      const int pw = (n == 0) ? pwA0 : (n == 1) ? pwA1 : (n == 2) ? pwA2     \
                                                                  : pwA3;   \
      *(uint2*)&Pl[pw] = w0;                                                 \
      *(uint2*)&Pl[pw + 1024] = w1;                                          \
    }                                                                        \
    L0 += rs0; L1 += rs1;                                                    \
    asm volatile("s_waitcnt lgkmcnt(0)" ::: "memory");                       \
    __builtin_amdgcn_sched_barrier(0);                                       \
    __builtin_amdgcn_s_setprio(1);                                           \
    {                                                                        \
      u16x8 pa00 = *(const u16x8*)&Pl[pbA0];                                 \
      u16x8 pa01 = *(const u16x8*)&Pl[pbA1];                                 \
      u16x8 pa10 = *(const u16x8*)&Pl[pbA0 + 1024];                          \
      u16x8 pa11 = *(const u16x8*)&Pl[pbA1 + 1024];                          \
      _Pragma("unroll") for (int nd = 0; nd < 4; ++nd) {                     \
        u16x8 va0 = *(const u16x8*)&VC[nd * 1024 + kb0];                     \
        u16x8 va1 = *(const u16x8*)&VC[nd * 1024 + kb1];                     \
        o20[nd] = MFMA(va0, pa00, o20[nd]);                                  \
        o20[nd] = MFMA(va1, pa01, o20[nd]);                                  \
        o21[nd] = MFMA(va0, pa10, o21[nd]);                                  \
        o21[nd] = MFMA(va1, pa11, o21[nd]);                                  \
      }                                                                      \
    }                                                                        \
    __builtin_amdgcn_s_setprio(0);                                           \
    __syncthreads();                                                         \
  }

  STAGE(Kl0, Vl0);
  __syncthreads();

#pragma unroll 1
  for (int it = 0; it < 16; ++it) {
    BODY(Kl0, Vl0, Kl1, Vl1);
    BODY(Kl1, Vl1, Kl0, Vl0);
  }

  L0 += __shfl_xor(L0, 16);
  L0 += __shfl_xor(L0, 32);
  L1 += __shfl_xor(L1, 16);
  L1 += __shfl_xor(L1, 32);
  const float inv0 = 1.f / L0, inv1 = 1.f / L1;
  const int b = bh >> 4, h = bh & (H_ - 1);
#pragma unroll
  for (int nd = 0; nd < 4; ++nd) {
    ushort4 w;
    w.x = f2b(o20[nd][0] * inv0);
    w.y = f2b(o20[nd][1] * inv0);
    w.z = f2b(o20[nd][2] * inv0);
    w.w = f2b(o20[nd][3] * inv0);
    *(ushort4*)(AO + ((size_t)(b * S_ + qr0 + c)) * D_ + h * HD_ + nd * 16 +
                g * 4) = w;
    ushort4 w2;
    w2.x = f2b(o21[nd][0] * inv1);
    w2.y = f2b(o21[nd][1] * inv1);
    w2.z = f2b(o21[nd][2] * inv1);
    w2.w = f2b(o21[nd][3] * inv1);
    *(ushort4*)(AO + ((size_t)(b * S_ + qr0 + 16 + c)) * D_ + h * HD_ +
                nd * 16 + g * 4) = w2;
  }
#undef BODY
#undef STAGE
}

extern "C" void kernel_launch(void* const* d_in, const int* in_sizes, int n_in,
                              void* d_out, int out_size, void* d_ws,
                              size_t ws_size, hipStream_t stream) {
  const float* x  = (const float*)d_in[0];
  const float* Wq = (const float*)d_in[1];
  const float* bq = (const float*)d_in[2];
  const float* Wk = (const float*)d_in[3];
  const float* bk = (const float*)d_in[4];
  const float* Wv = (const float*)d_in[5];
  const float* bv = (const float*)d_in[6];
  const float* W0 = (const float*)d_in[7];
  const float* b0 = (const float*)d_in[8];
  float* out = (float*)d_out;

  char* ws = (char*)d_ws;
  const size_t MiB = (size_t)1 << 20;
  float2* tab = (float2*)(ws + 0);          // 8 MiB
  u16* xb  = (u16*)(ws + 8 * MiB);          // 16 MiB
  u16* WqT = (u16*)(ws + 24 * MiB);         // 2 MiB each, contiguous WT3
  u16* WkT = (u16*)(ws + 26 * MiB);
  u16* WvT = (u16*)(ws + 28 * MiB);
  u16* W0T = (u16*)(ws + 30 * MiB);
  u16* Qh  = (u16*)(ws + 32 * MiB);         // 16 MiB each
  u16* Kh  = (u16*)(ws + 48 * MiB);         // [B,H,S,HD]
  u16* Vt  = (u16*)(ws + 64 * MiB);         // [B,H,HD,S]
  u16* AO  = (u16*)(ws + 80 * MiB);         // 16 MiB, [B,S,D]

  k_prep<<<16384, 256, 0, stream>>>(x, xb, Wq, Wk, Wv, W0,
                                    WqT, WkT, WvT, W0T, tab);
  k_gemm256_qkv<<<384, 512, 0, stream>>>(xb, WqT, bq, bk, bv, tab, Qh, Kh, Vt);
  k_attn<<<512, 512, 0, stream>>>(Qh, Kh, Vt, AO);
  k_gemm_o<<<dim3(64, 8), 256, 0, stream>>>(AO, W0T, b0, out);
}

// Round 15
// 187.233 us; speedup vs baseline: 1.0918x; 1.0918x over previous
//
#include <hip/hip_runtime.h>
#include <hip/hip_bf16.h>

typedef unsigned short u16;
typedef u16 u16x8 __attribute__((ext_vector_type(8)));
typedef float f32x4 __attribute__((ext_vector_type(4)));
typedef __bf16 bf16x8 __attribute__((ext_vector_type(8)));

#define B_ 4
#define S_ 2048
#define D_ 1024
#define H_ 16
#define HD_ 64
#define M_ (B_*S_)

#if __has_builtin(__builtin_amdgcn_exp2f)
#define EXP2(x) __builtin_amdgcn_exp2f(x)
#else
#define EXP2(x) exp2f(x)
#endif

__device__ __forceinline__ f32x4 MFMA(u16x8 a, u16x8 b, f32x4 c) {
  return __builtin_amdgcn_mfma_f32_16x16x32_bf16(
      __builtin_bit_cast(bf16x8, a), __builtin_bit_cast(bf16x8, b), c, 0, 0, 0);
}

__device__ __forceinline__ u16 f2b(float f) {
  return __builtin_bit_cast(u16, __float2bfloat16(f));
}

__device__ __forceinline__ void load_lds16(const void* g, void* l) {
  __builtin_amdgcn_global_load_lds(
      (const __attribute__((address_space(1))) void*)g,
      (__attribute__((address_space(3))) void*)l, 16, 0, 0);
}

__device__ __forceinline__ unsigned int cvtpk(float lo, float hi) {
  unsigned int r;
  asm("v_cvt_pk_bf16_f32 %0, %1, %2" : "=v"(r) : "v"(lo), "v"(hi));
  return r;
}

// ======== Fused prep: rope table | f32->bf16 cvt | 4x W transpose ========
__global__ __launch_bounds__(256) void k_prep(
    const float* __restrict__ x, u16* __restrict__ xb,
    const float* __restrict__ Wq, const float* __restrict__ Wk,
    const float* __restrict__ Wv, const float* __restrict__ W0,
    u16* __restrict__ Tq, u16* __restrict__ Tk, u16* __restrict__ Tv,
    u16* __restrict__ T0, float2* __restrict__ tab) {
  __shared__ float t[32][33];
  const int bid = blockIdx.x;
  const int tid = threadIdx.x;
  if (bid < 4096) {
    int i = bid * 256 + tid;
    int s = i >> 9;
    int f = i & 511;
    float invf = exp2f((float)f * (-13.287712379549449f / 512.0f));
    float ang = (float)s * invf;
    tab[i] = make_float2(cosf(ang), sinf(ang));
  } else if (bid < 12288) {
    int i = (bid - 4096) * 256 + tid;
    float4 v = ((const float4*)x)[i];
    ushort4 o;
    o.x = f2b(v.x); o.y = f2b(v.y); o.z = f2b(v.z); o.w = f2b(v.w);
    ((ushort4*)xb)[i] = o;
  } else {
    const int bid2 = bid - 12288;
    const int z = bid2 >> 10, rem = bid2 & 1023;
    const float* W = (z == 0) ? Wq : (z == 1) ? Wk : (z == 2) ? Wv : W0;
    u16* WT = (z == 0) ? Tq : (z == 1) ? Tk : (z == 2) ? Tv : T0;
    const int tx = tid & 31, ty = tid >> 5;  // 32 x 8
    const int bx = (rem & 31) * 32, by = (rem >> 5) * 32;
#pragma unroll
    for (int j = 0; j < 32; j += 8)
      t[ty + j][tx] = W[(size_t)(by + ty + j) * D_ + bx + tx];
    __syncthreads();
#pragma unroll
    for (int j = 0; j < 32; j += 8)
      WT[(size_t)(bx + ty + j) * D_ + by + tx] = f2b(t[tx][ty + j]);
  }
}

// ====== Fused QKV GEMM: 128x128 m97-style (best measured for QKV) ========
// grid 1536 blocks at 2 blk/CU = 3 exact dispatch rounds. XCD swizzle.
__global__ __launch_bounds__(256, 2) void k_gemm_qkv(
    const u16* __restrict__ A, const u16* __restrict__ WT3,
    const float* __restrict__ bq, const float* __restrict__ bk,
    const float* __restrict__ bv, const float2* __restrict__ tab,
    u16* __restrict__ Qh, u16* __restrict__ Kh, u16* __restrict__ Vt) {
  __shared__ __attribute__((aligned(16))) u16 Al[128 * 64];
  __shared__ __attribute__((aligned(16))) u16 Bl[128 * 64];
  const int tid = threadIdx.x;
  const int lane = tid & 63, wid = tid >> 6;
  const int wr = wid >> 1, wc = wid & 1;
  const int g = lane >> 4, c = lane & 15;
  const int flat = blockIdx.y * gridDim.x + blockIdx.x;
  const int xcd = flat & 7, idx = flat >> 3;
  const int bx = xcd * 8 + (idx & 7), by = idx >> 3;  // bx<64, by<24
  const int rowbase = bx * 128;
  const int colbaseG = by * 128;
  const int mode = by >> 3;
  const int colbase = colbaseG & 1023;

  f32x4 acc[4][4] = {};
  const int ldr = lane >> 3;
  const int ldk = (lane & 7) * 8;

  for (int kt = 0; kt < D_; kt += 64) {
    __syncthreads();
#pragma unroll
    for (int j = 0; j < 4; ++j) {
      const int chunk = wid * 4 + j;
      const int rr = chunk * 8 + ldr;
      load_lds16(A + (size_t)(rowbase + rr) * D_ + kt + ldk, &Al[chunk * 512]);
      load_lds16(WT3 + (size_t)(colbaseG + rr) * D_ + kt + ldk, &Bl[chunk * 512]);
    }
    __syncthreads();
#pragma unroll
    for (int ks = 0; ks < 2; ++ks) {
      u16x8 a[4], b[4];
#pragma unroll
      for (int m = 0; m < 4; ++m)
        a[m] = *(const u16x8*)&Al[(wr * 64 + m * 16 + c) * 64 + ks * 32 + g * 8];
#pragma unroll
      for (int n = 0; n < 4; ++n)
        b[n] = *(const u16x8*)&Bl[(wc * 64 + n * 16 + c) * 64 + ks * 32 + g * 8];
#pragma unroll
      for (int m = 0; m < 4; ++m)
#pragma unroll
        for (int n = 0; n < 4; ++n)
          acc[m][n] = MFMA(a[m], b[n], acc[m][n]);
    }
  }

  const float* bias = (mode == 0) ? bq : (mode == 1) ? bk : bv;
  u16* Cout = (mode == 0) ? Qh : (mode == 1) ? Kh : Vt;

  int coln[4];
  float bn[4];
#pragma unroll
  for (int n = 0; n < 4; ++n) {
    coln[n] = colbase + wc * 64 + n * 16 + c;
    bn[n] = bias[coln[n]];
  }

  if (mode == 2) {
#pragma unroll
    for (int m = 0; m < 4; ++m) {
      const int row0 = rowbase + wr * 64 + m * 16 + g * 4;
      const int s0 = row0 & (S_ - 1);
      const int bidx = row0 >> 11;
#pragma unroll
      for (int n = 0; n < 4; ++n) {
        const int h = coln[n] >> 6, hd = coln[n] & 63;
        ushort4 w;
        w.x = f2b(acc[m][n][0] + bn[n]);
        w.y = f2b(acc[m][n][1] + bn[n]);
        w.z = f2b(acc[m][n][2] + bn[n]);
        w.w = f2b(acc[m][n][3] + bn[n]);
        *(ushort4*)(Cout + ((size_t)(bidx * H_ + h) * HD_ + hd) * S_ + s0) = w;
      }
    }
  } else {
    const float qs = 0.18033688011112042f;  // 0.125 * log2(e)
#pragma unroll
    for (int m = 0; m < 4; ++m) {
#pragma unroll
      for (int r = 0; r < 4; ++r) {
        const int row = rowbase + wr * 64 + m * 16 + g * 4 + r;
        const int s = row & (S_ - 1);
        const int bidx = row >> 11;
#pragma unroll
        for (int n = 0; n < 4; ++n) {
          float v = acc[m][n][r] + bn[n];
          float2 cs = tab[(size_t)s * 512 + (coln[n] >> 1)];
          float nb = __shfl_xor(v, 1);
          v = (lane & 1) ? (nb * cs.y + v * cs.x) : (v * cs.x - nb * cs.y);
          if (mode == 0) v *= qs;
          const int h = coln[n] >> 6, hd = coln[n] & 63;
          Cout[(((size_t)(bidx * H_ + h)) * S_ + s) * HD_ + hd] = f2b(v);
        }
      }
    }
  }
}

// ------- Output GEMM: 128x128 m97-style, 2 blk/CU, grid 512 = 2 rounds ---
__global__ __launch_bounds__(256, 2) void k_gemm_o(
    const u16* __restrict__ A, const u16* __restrict__ BT,
    const float* __restrict__ bias, float* __restrict__ Cout) {
  __shared__ __attribute__((aligned(16))) u16 Al[128 * 64];
  __shared__ __attribute__((aligned(16))) u16 Bl[128 * 64];
  const int tid = threadIdx.x;
  const int lane = tid & 63, wid = tid >> 6;
  const int wr = wid >> 1, wc = wid & 1;
  const int g = lane >> 4, c = lane & 15;
  const int flat = blockIdx.y * gridDim.x + blockIdx.x;
  const int xcd = flat & 7, idx = flat >> 3;
  const int bx = xcd * 8 + (idx & 7), by = idx >> 3;  // bx<64, by<8
  const int rowbase = bx * 128, colbase = by * 128;

  f32x4 acc[4][4] = {};
  const int ldr = lane >> 3;
  const int ldk = (lane & 7) * 8;

  for (int kt = 0; kt < D_; kt += 64) {
    __syncthreads();
#pragma unroll
    for (int j = 0; j < 4; ++j) {
      const int chunk = wid * 4 + j;
      const int rr = chunk * 8 + ldr;
      load_lds16(A + (size_t)(rowbase + rr) * D_ + kt + ldk, &Al[chunk * 512]);
      load_lds16(BT + (size_t)(colbase + rr) * D_ + kt + ldk, &Bl[chunk * 512]);
    }
    __syncthreads();
#pragma unroll
    for (int ks = 0; ks < 2; ++ks) {
      u16x8 a[4], b[4];
#pragma unroll
      for (int m = 0; m < 4; ++m)
        a[m] = *(const u16x8*)&Al[(wr * 64 + m * 16 + c) * 64 + ks * 32 + g * 8];
#pragma unroll
      for (int n = 0; n < 4; ++n)
        b[n] = *(const u16x8*)&Bl[(wc * 64 + n * 16 + c) * 64 + ks * 32 + g * 8];
#pragma unroll
      for (int m = 0; m < 4; ++m)
#pragma unroll
        for (int n = 0; n < 4; ++n)
          acc[m][n] = MFMA(a[m], b[n], acc[m][n]);
    }
  }

  int coln[4];
  float bn[4];
#pragma unroll
  for (int n = 0; n < 4; ++n) {
    coln[n] = colbase + wc * 64 + n * 16 + c;
    bn[n] = bias[coln[n]];
  }
#pragma unroll
  for (int m = 0; m < 4; ++m)
#pragma unroll
    for (int r = 0; r < 4; ++r) {
      const int row = rowbase + wr * 64 + m * 16 + g * 4 + r;
#pragma unroll
      for (int n = 0; n < 4; ++n)
        Cout[(size_t)row * D_ + coln[n]] = acc[m][n][r] + bn[n];
    }
}

// ---------------- Flash attention v9 (best measured, ~84 us) ------------
__global__ __launch_bounds__(512, 4) void k_attn(const u16* __restrict__ Qh,
                                                 const u16* __restrict__ Kh,
                                                 const u16* __restrict__ Vt,
                                                 u16* __restrict__ AO) {
  __shared__ __attribute__((aligned(16))) u16 Kl0[4096], Kl1[4096];
  __shared__ __attribute__((aligned(16))) u16 Vl0[4096], Vl1[4096];
  __shared__ __attribute__((aligned(16))) u16 Pl[16384];
  const int tid = threadIdx.x;
  const int lane = tid & 63, wid = tid >> 6;
  const int g = lane >> 4, c = lane & 15;
  const int flat = blockIdx.x;
  const int swzid = (flat & 7) * 64 + (flat >> 3);
  const int bh = swzid >> 3, qt = swzid & 7;
  const size_t base = (size_t)bh * S_ * HD_;
  const int qr0 = qt * 256 + wid * 32;

  u16x8 qf[2][2];
#pragma unroll
  for (int qg = 0; qg < 2; ++qg)
#pragma unroll
    for (int ks = 0; ks < 2; ++ks)
      qf[qg][ks] = *(const u16x8*)(Qh + base +
                                   (size_t)(qr0 + qg * 16 + c) * HD_ +
                                   ks * 32 + g * 8);

  f32x4 o20[4] = {}, o21[4] = {};
  float L0 = 0.f, L1 = 0.f;

  const int swz = (c & 7) << 3;
  const int kb0 = c * 64 + ((g * 8) ^ swz);
  const int kb1 = c * 64 + ((32 + g * 8) ^ swz);
  const int pwA0 = wid * 2048 + ((c * 64 + 0 * 16 + g * 4) ^ swz);
  const int pwA1 = wid * 2048 + ((c * 64 + 1 * 16 + g * 4) ^ swz);
  const int pwA2 = wid * 2048 + ((c * 64 + 2 * 16 + g * 4) ^ swz);
  const int pwA3 = wid * 2048 + ((c * 64 + 3 * 16 + g * 4) ^ swz);
  const int pbA0 = wid * 2048 + kb0;
  const int pbA1 = wid * 2048 + kb1;
  const f32x4 z4 = {0.f, 0.f, 0.f, 0.f};

  const int ldrow = lane >> 3, ldslot = lane & 7;
  const int srow = wid * 8 + ldrow;
  const u16* kp0 = Kh + base + (size_t)srow * HD_ + (ldslot ^ (srow & 7)) * 8;
  const u16* vp0 = Vt + base + (size_t)srow * S_ + (ldslot ^ (srow & 7)) * 8;
  const int kdst0 = wid * 512;

#define STAGE(KP, VP)                                                        \
  {                                                                          \
    load_lds16(kp0, &KP[kdst0]); kp0 += 64 * HD_;                            \
    load_lds16(vp0, &VP[kdst0]); vp0 += 64;                                  \
  }

#define BODY(KC, VC, KP, VP)                                                 \
  {                                                                          \
    STAGE(KP, VP);                                                           \
    f32x4 s40[4], s41[4];                                                    \
    __builtin_amdgcn_s_setprio(1);                                           \
    _Pragma("unroll") for (int n = 0; n < 4; ++n) {                          \
      u16x8 kfa = *(const u16x8*)&KC[n * 1024 + kb0];                        \
      u16x8 kfb = *(const u16x8*)&KC[n * 1024 + kb1];                        \
      s40[n] = MFMA(kfa, qf[0][0], z4);                                      \
      s40[n] = MFMA(kfb, qf[0][1], s40[n]);                                  \
      s41[n] = MFMA(kfa, qf[1][0], z4);                                      \
      s41[n] = MFMA(kfb, qf[1][1], s41[n]);                                  \
    }                                                                        \
    __builtin_amdgcn_s_setprio(0);                                           \
    float rs0 = 0.f, rs1 = 0.f;                                              \
    _Pragma("unroll") for (int n = 0; n < 4; ++n) {                          \
      float p0[4], p1[4];                                                    \
      _Pragma("unroll") for (int r = 0; r < 4; ++r) {                        \
        p0[r] = EXP2(s40[n][r]); rs0 += p0[r];                               \
        p1[r] = EXP2(s41[n][r]); rs1 += p1[r];                               \
      }                                                                      \
      uint2 w0, w1;                                                          \
      w0.x = cvtpk(p0[0], p0[1]); w0.y = cvtpk(p0[2], p0[3]);                \
      w1.x = cvtpk(p1[0], p1[1]); w1.y = cvtpk(p1[2], p1[3]);                \
      const int pw = (n == 0) ? pwA0 : (n == 1) ? pwA1 : (n == 2) ? pwA2     \
                                                                  : pwA3;   \
      *(uint2*)&Pl[pw] = w0;                                                 \
      *(uint2*)&Pl[pw + 1024] = w1;                                          \
    }                                                                        \
    L0 += rs0; L1 += rs1;                                                    \
    asm volatile("s_waitcnt lgkmcnt(0)" ::: "memory");                       \
    __builtin_amdgcn_sched_barrier(0);                                       \
    __builtin_amdgcn_s_setprio(1);                                           \
    {                                                                        \
      u16x8 pa00 = *(const u16x8*)&Pl[pbA0];                                 \
      u16x8 pa01 = *(const u16x8*)&Pl[pbA1];                                 \
      u16x8 pa10 = *(const u16x8*)&Pl[pbA0 + 1024];                          \
      u16x8 pa11 = *(const u16x8*)&Pl[pbA1 + 1024];                          \
      _Pragma("unroll") for (int nd = 0; nd < 4; ++nd) {                     \
        u16x8 va0 = *(const u16x8*)&VC[nd * 1024 + kb0];                     \
        u16x8 va1 = *(const u16x8*)&VC[nd * 1024 + kb1];                     \
        o20[nd] = MFMA(va0, pa00, o20[nd]);                                  \
        o20[nd] = MFMA(va1, pa01, o20[nd]);                                  \
        o21[nd] = MFMA(va0, pa10, o21[nd]);                                  \
        o21[nd] = MFMA(va1, pa11, o21[nd]);                                  \
      }                                                                      \
    }                                                                        \
    __builtin_amdgcn_s_setprio(0);                                           \
    __syncthreads();                                                         \
  }

  STAGE(Kl0, Vl0);
  __syncthreads();

#pragma unroll 1
  for (int it = 0; it < 16; ++it) {
    BODY(Kl0, Vl0, Kl1, Vl1);
    BODY(Kl1, Vl1, Kl0, Vl0);
  }

  L0 += __shfl_xor(L0, 16);
  L0 += __shfl_xor(L0, 32);
  L1 += __shfl_xor(L1, 16);
  L1 += __shfl_xor(L1, 32);
  const float inv0 = 1.f / L0, inv1 = 1.f / L1;
  const int b = bh >> 4, h = bh & (H_ - 1);
#pragma unroll
  for (int nd = 0; nd < 4; ++nd) {
    ushort4 w;
    w.x = f2b(o20[nd][0] * inv0);
    w.y = f2b(o20[nd][1] * inv0);
    w.z = f2b(o20[nd][2] * inv0);
    w.w = f2b(o20[nd][3] * inv0);
    *(ushort4*)(AO + ((size_t)(b * S_ + qr0 + c)) * D_ + h * HD_ + nd * 16 +
                g * 4) = w;
    ushort4 w2;
    w2.x = f2b(o21[nd][0] * inv1);
    w2.y = f2b(o21[nd][1] * inv1);
    w2.z = f2b(o21[nd][2] * inv1);
    w2.w = f2b(o21[nd][3] * inv1);
    *(ushort4*)(AO + ((size_t)(b * S_ + qr0 + 16 + c)) * D_ + h * HD_ +
                nd * 16 + g * 4) = w2;
  }
#undef BODY
#undef STAGE
}

extern "C" void kernel_launch(void* const* d_in, const int* in_sizes, int n_in,
                              void* d_out, int out_size, void* d_ws,
                              size_t ws_size, hipStream_t stream) {
  const float* x  = (const float*)d_in[0];
  const float* Wq = (const float*)d_in[1];
  const float* bq = (const float*)d_in[2];
  const float* Wk = (const float*)d_in[3];
  const float* bk = (const float*)d_in[4];
  const float* Wv = (const float*)d_in[5];
  const float* bv = (const float*)d_in[6];
  const float* W0 = (const float*)d_in[7];
  const float* b0 = (const float*)d_in[8];
  float* out = (float*)d_out;

  char* ws = (char*)d_ws;
  const size_t MiB = (size_t)1 << 20;
  float2* tab = (float2*)(ws + 0);          // 8 MiB
  u16* xb  = (u16*)(ws + 8 * MiB);          // 16 MiB
  u16* WqT = (u16*)(ws + 24 * MiB);         // 2 MiB each, contiguous WT3
  u16* WkT = (u16*)(ws + 26 * MiB);
  u16* WvT = (u16*)(ws + 28 * MiB);
  u16* W0T = (u16*)(ws + 30 * MiB);
  u16* Qh  = (u16*)(ws + 32 * MiB);         // 16 MiB each
  u16* Kh  = (u16*)(ws + 48 * MiB);         // [B,H,S,HD]
  u16* Vt  = (u16*)(ws + 64 * MiB);         // [B,H,HD,S]
  u16* AO  = (u16*)(ws + 80 * MiB);         // 16 MiB, [B,S,D]

  k_prep<<<16384, 256, 0, stream>>>(x, xb, Wq, Wk, Wv, W0,
                                    WqT, WkT, WvT, W0T, tab);
  k_gemm_qkv<<<dim3(64, 24), 256, 0, stream>>>(xb, WqT, bq, bk, bv, tab,
                                               Qh, Kh, Vt);
  k_attn<<<512, 512, 0, stream>>>(Qh, Kh, Vt, AO);
  k_gemm_o<<<dim3(64, 8), 256, 0, stream>>>(AO, W0T, b0, out);
}